// Round 8
// baseline (200.008 us; speedup 1.0000x reference)
//
#include <hip/hip_runtime.h>

// PureQNet fused single kernel: pool(64x64->4x4) -> normalize -> fixed 16x16
// circuit unitary -> |psi|^2 -> 10x16 head -> *scale.
// The depth-6 circuit + Z-sign head are input-independent: every block
// recomputes the tiny tables in LDS (24 sincosf, hidden under the image
// loads), then each WAVE processes one image independently.
// All cross-lane data movement after the pooling butterfly goes through LDS
// with block barriers (pass-proven pattern); no shuffle redistribution.
//
// ltab layout (row stride US=17: bank-conflict-free for 16-row reads):
//   [0..272)   Ure[16][17]
//   [272..544) Uim[16][17]
//   [544..714) M2 [10][17]   M2[r][j] = sum_k head_w[r][k] * Zsign_k(j)

#define US 17
#define TAB_N 714

__global__ __launch_bounds__(256) void qnet_fused(
    const float* __restrict__ x,        // (B,1,64,64)
    const float* __restrict__ qw,       // (6,4)
    const float* __restrict__ head_w,   // (10,10)
    const float* __restrict__ head_b,   // (10,)
    const float* __restrict__ scale,    // (1,)
    float* __restrict__ out,            // (B,10)
    int B)
{
    __shared__ float ltab[TAB_N];
    __shared__ float pool_s[4][16];
    __shared__ float prob_s[4][16];

    const int t  = threadIdx.x;
    const int wv = t >> 6;
    const int ln = t & 63;
    const int m  = ln & 15;

    const int ib  = blockIdx.x * 4 + wv;          // one image per wave
    const int ibc = (ib < B) ? ib : 0;
    const float* img = x + (size_t)ibc * 4096;

    // ---- phase 1: pooling. lane ln, load i -> elements 4*ln + 256*i .. +3
    // row = (ln>>4) + 4i, cols [4m,4m+3]; all 4 floats share bin
    // (i>>2, m>>2). Class over lane-bits {0,1,4,5} completes each 16x16 bin.
    float s0 = 0.f, s1 = 0.f, s2 = 0.f, s3 = 0.f;
#pragma unroll
    for (int i = 0; i < 16; ++i) {
        const float4 u = *reinterpret_cast<const float4*>(img + 4 * ln + 256 * i);
        const float r = (u.x + u.y) + (u.z + u.w);
        if (i < 4)       s0 += r;
        else if (i < 8)  s1 += r;
        else if (i < 12) s2 += r;
        else             s3 += r;
    }
    s0 += __shfl_xor(s0, 1); s0 += __shfl_xor(s0, 2);
    s0 += __shfl_xor(s0, 16); s0 += __shfl_xor(s0, 32);
    s1 += __shfl_xor(s1, 1); s1 += __shfl_xor(s1, 2);
    s1 += __shfl_xor(s1, 16); s1 += __shfl_xor(s1, 32);
    s2 += __shfl_xor(s2, 1); s2 += __shfl_xor(s2, 2);
    s2 += __shfl_xor(s2, 16); s2 += __shfl_xor(s2, 32);
    s3 += __shfl_xor(s3, 1); s3 += __shfl_xor(s3, 2);
    s3 += __shfl_xor(s3, 16); s3 += __shfl_xor(s3, 32);

    // lanes 0,4,8,12 hold complete sums for col-bin cb = ln>>2
    if (ln < 16 && (ln & 3) == 0) {
        const int cb = ln >> 2;
        pool_s[wv][ 0 + cb] = s0 * (1.f / 256.f);   // v[4*rowbin + colbin]
        pool_s[wv][ 4 + cb] = s1 * (1.f / 256.f);
        pool_s[wv][ 8 + cb] = s2 * (1.f / 256.f);
        pool_s[wv][12 + cb] = s3 * (1.f / 256.f);
    }

    // ---- phase 2: tables. 16-lane group evolves basis state k = t>>4 ----
    {
        const int k   = t >> 4;
        const int idx = t & 15;                     // amplitude idx, wire0=MSB
        float re = (idx == k) ? 1.f : 0.f;
        float im = 0.f;
#pragma unroll
        for (int layer = 0; layer < 6; ++layer) {
#pragma unroll
            for (int q = 0; q < 4; ++q) {           // RX(qw[layer][q]) on wire q
                const float half = 0.5f * qw[layer * 4 + q];
                float sn, cs;
                sincosf(half, &sn, &cs);
                const int bit = 1 << (3 - q);
                const float re_p = __shfl_xor(re, bit);
                const float im_p = __shfl_xor(im, bit);
                re = cs * re + sn * im_p;           // new = c*self - i*s*partner
                im = cs * im - sn * re_p;
            }
#pragma unroll
            for (int q = 0; q < 4; ++q) {           // CNOT(q -> (q+1)%4)
                const int cbit = 1 << (3 - q);
                const int tbit = 1 << (3 - ((q + 1) & 3));
                const float re_s = __shfl_xor(re, tbit);
                const float im_s = __shfl_xor(im, tbit);
                const bool c1 = (idx & cbit) != 0;
                re = c1 ? re_s : re;
                im = c1 ? im_s : im;
            }
        }
        ltab[idx * US + k]       = re;
        ltab[272 + idx * US + k] = im;

        if (t < 160) {                              // M2[r][j]
            const int r = t >> 4, j = t & 15;
            const float z0 = (j & 8) ? -1.f : 1.f;
            const float z1 = (j & 4) ? -1.f : 1.f;
            const float z2 = (j & 2) ? -1.f : 1.f;
            const float z3 = (j & 1) ? -1.f : 1.f;
            const float* hw = head_w + r * 10;
            ltab[544 + r * US + j] =
                  z0 * hw[0] + z1 * hw[1] + z2 * hw[2] + z3 * hw[3]
                + (z0 * z1) * hw[4] + (z0 * z2) * hw[5] + (z0 * z3) * hw[6]
                + (z1 * z2) * hw[7] + (z1 * z3) * hw[8] + (z2 * z3) * hw[9];
        }
    }
    __syncthreads();                                // ltab + pool_s visible

    // ---- phase 3: psi[m] = sum_k U[m][k]*v[k]; prob = |psi|^2 / sum v^2 ----
    float sre = 0.f, sim = 0.f, n2 = 0.f;
#pragma unroll
    for (int k = 0; k < 16; ++k) {
        const float a = pool_s[wv][k];              // LDS broadcast
        n2  = fmaf(a, a, n2);
        sre = fmaf(ltab[m * US + k], a, sre);
        sim = fmaf(ltab[272 + m * US + k], a, sim);
    }
    const float prob = (sre * sre + sim * sim) / n2;
    if (ln < 16) prob_s[wv][ln] = prob;
    __syncthreads();                                // prob_s visible

    // ---- phase 4: head ----
    if (ln < 10 && ib < B) {
        float acc = 0.f;
#pragma unroll
        for (int j = 0; j < 16; ++j)
            acc = fmaf(ltab[544 + ln * US + j], prob_s[wv][j], acc);
        out[(size_t)ib * 10 + ln] = (acc + head_b[ln]) * scale[0];
    }
}

extern "C" void kernel_launch(void* const* d_in, const int* in_sizes, int n_in,
                              void* d_out, int out_size, void* d_ws, size_t ws_size,
                              hipStream_t stream) {
    const float* x      = (const float*)d_in[0];
    const float* qw     = (const float*)d_in[1];
    const float* head_w = (const float*)d_in[2];
    const float* head_b = (const float*)d_in[3];
    const float* scale  = (const float*)d_in[4];
    float* out = (float*)d_out;

    const int B = in_sizes[0] / 4096;   // 8192
    qnet_fused<<<(B + 3) / 4, 256, 0, stream>>>(x, qw, head_w, head_b, scale, out, B);
}